// Round 6
// baseline (633.464 us; speedup 1.0000x reference)
//
#include <hip/hip_runtime.h>
#include <hip/hip_bf16.h>

#define HH 96
#define WW 160
#define BATCH 8
#define NPIX (BATCH*HH*WW)   // 122880
#define CIN 256
#define IMG (HH*WW)          // 15360
#define PW 162               // padded width
#define PH 98                // padded height
#define PR (PH*PW)           // 15876 padded rows per image
#define PTOT (BATCH*PR)      // 127008 padded rows total

typedef short bf16x8 __attribute__((ext_vector_type(8)));
typedef float f32x4 __attribute__((ext_vector_type(4)));

__device__ __forceinline__ unsigned short f2bf(float f) {
    unsigned int u = __float_as_uint(f);
    u = (u + 0x7fffu + ((u >> 16) & 1u)) >> 16;   // RNE
    return (unsigned short)u;
}

__device__ __forceinline__ void gload16(const void* g, void* l) {
    __builtin_amdgcn_global_load_lds(
        (const __attribute__((address_space(1))) void*)g,
        (__attribute__((address_space(3))) void*)l,
        16, 0, 0);
}

// ---------------- merged prep: weights pack + pad zero + depth-acc zero + BN fold + feature pack ----
// All five prep tasks are mutually independent (disjoint outputs), so one launch removes 3-4
// serial kernel boundaries and overlaps the small tasks with pack_features' tail.
// Block roles by blockIdx.x:
//   [0, 5760)        : pack weights OIHW f32 -> [cout][pos][cin] bf16 (w1T | w2T | uw1T)
//   [5760, 9888)     : zero pad rows of featP/h1P (2 of the original 128-thread tasks per block)
//   [9888, 10368)    : zero depth accumulator out[0..NPIX)
//   10368            : BN fold scalars
//   [10369, 41089)   : NCHW f32 -> padded NHWC bf16 (original dim3(5,8,768) linearized)
__global__ __launch_bounds__(256) void prep_all(
    const float* __restrict__ w1, const float* __restrict__ w2, const float* __restrict__ uw1,
    unsigned short* __restrict__ w1T, unsigned short* __restrict__ w2T, unsigned short* __restrict__ uw1T,
    unsigned int* __restrict__ featPu, unsigned int* __restrict__ h1Pu, float* __restrict__ outd,
    const float* __restrict__ b1, const float* __restrict__ g1, const float* __restrict__ be1,
    const float* __restrict__ m1, const float* __restrict__ v1,
    const float* __restrict__ b2, const float* __restrict__ g2, const float* __restrict__ be2,
    const float* __restrict__ m2, const float* __restrict__ v2,
    const float* __restrict__ ub1,
    float* __restrict__ scale1, float* __restrict__ bias1,
    float* __restrict__ scale2, float* __restrict__ bias2,
    const float* __restrict__ f, unsigned short* __restrict__ ft)
{
    __shared__ float tile[32][33];
    const int bid = blockIdx.x;
    const int t = threadIdx.x;

    if (bid < 5760) {
        const int S = 256 * 2304;       // 589824
        int i = bid * 256 + t;
        if (i < S) {
            int co = i / 2304, r = i % 2304, pos = r >> 8, ci = r & 255;
            w1T[i] = f2bf(w1[(co * 256 + ci) * 9 + pos]);
        } else if (i < 2 * S) {
            int j = i - S;
            int co = j / 2304, r = j % 2304, pos = r >> 8, ci = r & 255;
            w2T[j] = f2bf(w2[(co * 256 + ci) * 9 + pos]);
        } else {
            int j = i - 2 * S;          // < 128*2304
            int co = j / 2304, r = j % 2304, pos = r >> 8, ci = r & 255;
            uw1T[j] = f2bf(uw1[(co * 256 + ci) * 9 + pos]);
        }
    } else if (bid < 9888) {
        int k2 = (bid - 5760) * 2 + (t >> 7);   // 0..8255, two 128-lane tasks per block
        int lane = t & 127;
        unsigned int* buf = (k2 < 4128) ? featPu : h1Pu;
        int k = (k2 < 4128) ? k2 : (k2 - 4128);
        int img = k / 516, i = k % 516;
        int py, px;
        if (i < PW)            { py = 0;      px = i; }
        else if (i < 2 * PW)   { py = PH - 1; px = i - PW; }
        else { int q = i - 2 * PW; py = 1 + (q >> 1); px = (q & 1) ? (PW - 1) : 0; }
        size_t row = (size_t)img * PR + (size_t)py * PW + px;
        buf[row * 128 + lane] = 0;              // 512 B row of zeros
    } else if (bid < 10368) {
        outd[(size_t)(bid - 9888) * 256 + t] = 0.f;   // 480*256 = NPIX
    } else if (bid == 10368) {
        if (t < 256) {
            float s1 = g1[t] * rsqrtf(v1[t] + 1e-5f);
            scale1[t] = s1;
            bias1[t]  = (b1[t] - m1[t]) * s1 + be1[t];
            float s2 = g2[t] * rsqrtf(v2[t] + 1e-5f);
            scale2[t] = s2;
            bias2[t]  = (b2[t] - m2[t]) * s2 + be2[t];
            if (t < 128) { scale1[256 + t] = 1.0f; bias1[256 + t] = ub1[t]; }
        }
    } else {
        int id = bid - 10369;                   // 30720 pack blocks
        int x0 = (id % 5) * 32;                 // W/32 = 5
        int c0 = ((id / 5) % 8) * 32;           // C/32 = 8
        int by = id / 40;                       // B*H = 768
        int b = by / HH, y = by % HH;
        int tx = t & 31, tg = t >> 5;           // tg 0..7
        const float* src = f + (((size_t)(b * CIN + c0) * HH + y) * WW) + x0;
        #pragma unroll
        for (int i = 0; i < 4; ++i) {
            int cl = tg + i * 8;
            tile[cl][tx] = src[(size_t)cl * HH * WW + tx];
        }
        __syncthreads();
        size_t rbase = (size_t)b * PR + (size_t)(y + 1) * PW + (x0 + 1);
        #pragma unroll
        for (int i = 0; i < 4; ++i) {
            int xl = tg + i * 8;
            ft[(rbase + xl) * 256 + c0 + tx] = f2bf(tile[tx][xl]);
        }
    }
}

// ---------------- 3x3 conv, implicit GEMM, padded input, shared-dy B staging ----------------
// Occupancy ladder (verified r3/r5): <3> = 3 blocks/CU, MfmaUtil 46%, conv1 219us.
// <4> squeezed VGPR 76->64 and got 4 blocks resident (occ 38%) but conv1 REGRESSED to 227us:
// FETCH +52% / WRITE +51% — co-resident working set (43 spatial tiles x (B-rows 73KB + dirty
// out 65KB) ~ 5.9MB) exceeds the 4MB XCD L2 -> thrash. conv1 stays <3>.
// conv2 (mode 0) writes almost nothing (atomicAdd only), so the write half of that mechanism
// is absent -> this round A/Bs conv2 at <4> to isolate read-side thrash.
// XCD swizzle: 120 spatial blocks = exactly one image per XCD -> L2 locality.
// K loop = 8 cc-chunks x 3 dy; 24 barrier pairs, 48 MFMA/wave/pair.
// Row-wrap: pixel j with x0+j>=WW lives at padded addr r0+j+2.
// Swizzle (conflict-free): lane l stages row l>>2, quarter (l&3)^((l>>3)&3).
// mode 0: conv2 + FUSED depth head: per-block partial dot with w3 (passed via uw2) over this
//         block's 128 channels, one f32 atomicAdd per pixel into uout (2 contributors/pixel;
//         f32 add commutes -> deterministic). My=2.
// mode 1: merged conv1 (padded bf16 out, m0<256) + fused uncertainty head (m0==256), My=3.
template<int MINW>
__global__ __launch_bounds__(256, MINW) void conv3x3_mfma(
    const unsigned short* __restrict__ inP,
    const unsigned short* __restrict__ wT,
    const float* __restrict__ scale, const float* __restrict__ bias,
    unsigned short* __restrict__ outT,
    float* __restrict__ uout,
    const float* __restrict__ uw2, const float* __restrict__ ub2,
    int Cout, int mode, int My)
{
    __shared__ unsigned short Alds[3 * 128 * 32];   // 24576 B, [pos][slot][...]
    __shared__ unsigned short Blds[144 * 32];       // 9216 B
    __shared__ float usum[2][128];

    const int t = threadIdx.x;
    const int wave = t >> 6;
    const int l = t & 63;

    const int lid = blockIdx.x;
    const int xcd = lid & 7;
    const int j = lid >> 3;
    const int n0 = (xcd * 120 + j / My) * 128;
    const int m0 = (j % My) * 128;
    const bool is_unc = (mode == 1) && (m0 == 256);

    const int b0 = n0 / IMG;
    const int rem0 = n0 % IMG;
    const int y0 = rem0 / WW;
    const int x0 = rem0 % WW;
    const int r0 = b0 * PR + (y0 + 1) * PW + (x0 + 1);   // padded row of first output pixel

    const int lrow = l >> 2;
    const int lkq = (l & 3) ^ ((l >> 3) & 3);

    // A staging per-lane source bases (two 16-row slots per wave)
    const unsigned short* asrc0 = wT + (size_t)(m0 + wave * 32 + lrow) * 9 * 256 + lkq * 8;
    const unsigned short* asrc1 = asrc0 + (size_t)16 * 9 * 256;

    char* AldsB = (char*)Alds;
    char* BldsB = (char*)Blds;
    char* aldst = AldsB + wave * 2048;   // + dx*8192 (+1024 for second slot)

    const int wm = wave >> 1, wn = wave & 1;
    const int quad = l >> 4, lane16 = l & 15;
    const int aoff = lane16 * 64 + ((quad ^ ((lane16 >> 1) & 3)) << 4);

    // B fragment base tile-rows: pixel j -> r0 + j (+2 if wrapped); staging origin
    // rs = r0 + (dyi-1)*PW - 8; dx adds 0..2; base = j + wrap + 7
    int browbase[4];
    #pragma unroll
    for (int i = 0; i < 4; ++i) {
        int jj = wn * 64 + i * 16 + lane16;
        browbase[i] = jj + ((x0 + jj) >= WW ? 2 : 0) + 7;
    }

    f32x4 acc[4][4];
    #pragma unroll
    for (int mt = 0; mt < 4; ++mt)
        #pragma unroll
        for (int nt = 0; nt < 4; ++nt)
            acc[mt][nt] = (f32x4){0.f, 0.f, 0.f, 0.f};

    for (int cc = 0; cc < 8; ++cc) {
        const int ccoff = cc * 32;
        for (int dyi = 0; dyi < 3; ++dyi) {
            __syncthreads();
            // ---- stage A: 3 pos-tiles (pos = dyi*3 + dx), 6 instr/wave
            const unsigned short* a0 = asrc0 + (dyi * 3) * 256 + ccoff;
            const unsigned short* a1 = asrc1 + (dyi * 3) * 256 + ccoff;
            #pragma unroll
            for (int dxp = 0; dxp < 3; ++dxp) {
                gload16(a0 + dxp * 256, aldst + dxp * 8192);
                gload16(a1 + dxp * 256, aldst + dxp * 8192 + 1024);
            }
            // ---- stage B: 144 padded rows [r0 + (dyi-1)*PW - 8, +144), 9 slots
            const ptrdiff_t rs = (ptrdiff_t)r0 + (ptrdiff_t)(dyi - 1) * PW - 8;
            const unsigned short* bs = inP + (rs + lrow) * 256 + ccoff + lkq * 8
                                           + (size_t)wave * 8192;   // wave covers slots 2w,2w+1
            gload16(bs, BldsB + wave * 2048);
            gload16(bs + 4096, BldsB + wave * 2048 + 1024);
            if (wave == 3) gload16(bs + 8192, BldsB + 8192);        // slot 8
            __syncthreads();
            // ---- compute: 3 dx shifts x 16 MFMA
            #pragma unroll
            for (int dx = 0; dx < 3; ++dx) {
                bf16x8 af[4], bfr[4];
                #pragma unroll
                for (int mt = 0; mt < 4; ++mt)
                    af[mt] = *(const bf16x8*)(AldsB + dx * 8192 + ((wm * 4 + mt) << 10) + aoff);
                #pragma unroll
                for (int i = 0; i < 4; ++i) {
                    int row = browbase[i] + dx;
                    int ba = (row << 6) + ((quad ^ ((row >> 1) & 3)) << 4);
                    bfr[i] = *(const bf16x8*)(BldsB + ba);
                }
                #pragma unroll
                for (int mt = 0; mt < 4; ++mt)
                    #pragma unroll
                    for (int nt = 0; nt < 4; ++nt)
                        acc[mt][nt] = __builtin_amdgcn_mfma_f32_16x16x32_bf16(
                            af[mt], bfr[nt], acc[mt][nt], 0, 0, 0);
            }
        }
    }

    if (is_unc) {
        // fused uncertainty head: relu(acc+ub1) dot uw2 over all 128 channels -> softplus
        const float* ub = bias + 256;
        float s[4] = {0.f, 0.f, 0.f, 0.f};
        #pragma unroll
        for (int mt = 0; mt < 4; ++mt) {
            const int mg = wm * 64 + mt * 16 + quad * 4;
            const float4 bi = *(const float4*)&ub[mg];
            const float4 uw = *(const float4*)&uw2[mg];
            #pragma unroll
            for (int nt = 0; nt < 4; ++nt) {
                s[nt] += fmaxf(acc[mt][nt][0] + bi.x, 0.f) * uw.x
                       + fmaxf(acc[mt][nt][1] + bi.y, 0.f) * uw.y
                       + fmaxf(acc[mt][nt][2] + bi.z, 0.f) * uw.z
                       + fmaxf(acc[mt][nt][3] + bi.w, 0.f) * uw.w;
            }
        }
        #pragma unroll
        for (int nt = 0; nt < 4; ++nt) {
            s[nt] += __shfl_xor(s[nt], 16);
            s[nt] += __shfl_xor(s[nt], 32);
        }
        if (quad == 0) {
            #pragma unroll
            for (int nt = 0; nt < 4; ++nt)
                usum[wm][wn * 64 + nt * 16 + lane16] = s[nt];
        }
        __syncthreads();
        if (t < 128) {
            float x = usum[0][t] + usum[1][t] + ub2[0];
            uout[n0 + t] = fmaxf(x, 0.f) + log1pf(expf(-fabsf(x)));
        }
        return;
    }

    if (mode == 0) {
        // fused depth head: partial dot of relu(acc*scale+bias) with w3 (in uw2) over this
        // block's 128 channels; reduce quad via shfl, wm via LDS, one atomicAdd per pixel.
        float s[4] = {0.f, 0.f, 0.f, 0.f};
        #pragma unroll
        for (int mt = 0; mt < 4; ++mt) {
            const int mg = m0 + wm * 64 + mt * 16 + quad * 4;
            const float4 sc = *(const float4*)&scale[mg];
            const float4 bi = *(const float4*)&bias[mg];
            const float4 w  = *(const float4*)&uw2[mg];
            #pragma unroll
            for (int nt = 0; nt < 4; ++nt) {
                s[nt] += fmaxf(acc[mt][nt][0] * sc.x + bi.x, 0.f) * w.x
                       + fmaxf(acc[mt][nt][1] * sc.y + bi.y, 0.f) * w.y
                       + fmaxf(acc[mt][nt][2] * sc.z + bi.z, 0.f) * w.z
                       + fmaxf(acc[mt][nt][3] * sc.w + bi.w, 0.f) * w.w;
            }
        }
        #pragma unroll
        for (int nt = 0; nt < 4; ++nt) {
            s[nt] += __shfl_xor(s[nt], 16);
            s[nt] += __shfl_xor(s[nt], 32);
        }
        if (quad == 0) {
            #pragma unroll
            for (int nt = 0; nt < 4; ++nt)
                usum[wm][wn * 64 + nt * 16 + lane16] = s[nt];
        }
        __syncthreads();
        if (t < 128) atomicAdd(&uout[n0 + t], usum[0][t] + usum[1][t]);
        return;
    }

    // mode 1 conv output: y = relu(acc*scale + bias) -> bf16 padded rows
    size_t obase[4];
    #pragma unroll
    for (int nt = 0; nt < 4; ++nt) {
        int n = n0 + wn * 64 + nt * 16 + lane16;
        int b = n / IMG, rem = n % IMG, yy = rem / WW, xx = rem % WW;
        obase[nt] = ((size_t)(b * PH + yy + 1) * PW + (xx + 1)) * 256;
    }
    #pragma unroll
    for (int mt = 0; mt < 4; ++mt) {
        const int mg = m0 + wm * 64 + mt * 16 + quad * 4;
        const float4 sc = *(const float4*)&scale[mg];
        const float4 bi = *(const float4*)&bias[mg];
        #pragma unroll
        for (int nt = 0; nt < 4; ++nt) {
            ushort4 pk;
            pk.x = f2bf(fmaxf(acc[mt][nt][0] * sc.x + bi.x, 0.f));
            pk.y = f2bf(fmaxf(acc[mt][nt][1] * sc.y + bi.y, 0.f));
            pk.z = f2bf(fmaxf(acc[mt][nt][2] * sc.z + bi.z, 0.f));
            pk.w = f2bf(fmaxf(acc[mt][nt][3] * sc.w + bi.w, 0.f));
            *(ushort4*)&outT[obase[nt] + mg] = pk;
        }
    }
}

// ---------------- finalize depth: x -> 1/(0.01 + 9.99*sigmoid(x + b3)) in-place ----------------
__global__ __launch_bounds__(256) void depth_transform(
    float* __restrict__ out, const float* __restrict__ b3)
{
    int i = blockIdx.x * 256 + threadIdx.x;    // 480 * 256 = NPIX exactly
    float x = out[i] + b3[0];
    float sig = 1.f / (1.f + expf(-x));
    out[i] = 1.f / (0.01f + 9.99f * sig);
}

// ---------------- per-box lower-median via 4-pass radix select on float bits ----------------
__global__ __launch_bounds__(256) void median_kernel(
    const float* __restrict__ depth, const int* __restrict__ bboxes, float* __restrict__ obj)
{
    const int bi = blockIdx.x;          // b*64 + box
    const int b = bi >> 6;
    const int* bb = bboxes + (size_t)bi * 4;
    int x1 = max(bb[0], 0), y1 = max(bb[1], 0);
    int x2 = min(bb[2], WW), y2 = min(bb[3], HH);
    int w = x2 - x1, h = y2 - y1;
    if (w <= 0 || h <= 0) {
        if (threadIdx.x == 0) obj[bi] = 0.f;
        return;
    }
    const int wh = w * h;
    int tgt = (wh - 1) >> 1;            // lower median index
    const float* dbase = depth + (size_t)b * HH * WW;

    __shared__ unsigned int hist[256];
    __shared__ unsigned int sel_prefix, sel_target;
    unsigned int prefix = 0;

    for (int pass = 0; pass < 4; ++pass) {
        const int shift = 24 - 8 * pass;
        hist[threadIdx.x] = 0;
        __syncthreads();
        const unsigned int mask_high = (pass == 0) ? 0u : (0xFFFFFFFFu << (shift + 8));
        for (int idx = threadIdx.x; idx < wh; idx += 256) {
            int yy = y1 + idx / w, xx = x1 + idx % w;
            unsigned int uu = __float_as_uint(dbase[yy * WW + xx]);
            if ((uu & mask_high) == (prefix & mask_high))
                atomicAdd(&hist[(uu >> shift) & 255], 1u);
        }
        __syncthreads();
        if (threadIdx.x == 0) {
            unsigned int cum = 0;
            for (int bin = 0; bin < 256; ++bin) {
                unsigned int c = hist[bin];
                if (cum + c > (unsigned int)tgt) {
                    sel_target = (unsigned int)tgt - cum;
                    sel_prefix = prefix | ((unsigned int)bin << shift);
                    break;
                }
                cum += c;
            }
        }
        __syncthreads();
        prefix = sel_prefix;
        tgt = (int)sel_target;
    }
    if (threadIdx.x == 0) obj[bi] = __uint_as_float(prefix);
}

extern "C" void kernel_launch(void* const* d_in, const int* in_sizes, int n_in,
                              void* d_out, int out_size, void* d_ws, size_t ws_size,
                              hipStream_t stream) {
    const float* features = (const float*)d_in[0];
    const int*   bboxes   = (const int*)d_in[1];
    const float* w1  = (const float*)d_in[2];
    const float* b1  = (const float*)d_in[3];
    const float* g1  = (const float*)d_in[4];
    const float* be1 = (const float*)d_in[5];
    const float* m1  = (const float*)d_in[6];
    const float* v1  = (const float*)d_in[7];
    const float* w2  = (const float*)d_in[8];
    const float* b2  = (const float*)d_in[9];
    const float* g2  = (const float*)d_in[10];
    const float* be2 = (const float*)d_in[11];
    const float* m2  = (const float*)d_in[12];
    const float* v2  = (const float*)d_in[13];
    const float* w3  = (const float*)d_in[14];
    const float* b3  = (const float*)d_in[15];
    const float* uw1 = (const float*)d_in[16];
    const float* ub1 = (const float*)d_in[17];
    const float* uw2 = (const float*)d_in[18];
    const float* ub2 = (const float*)d_in[19];
    float* out = (float*)d_out;

    char* ws = (char*)d_ws;
    // layout (bytes). Padded buffers have 8 KB read-slack gaps on both sides.
    unsigned short* featP = (unsigned short*)(ws + 8192);        // 65,028,096 -> end 65,036,288
    unsigned short* h1P   = (unsigned short*)(ws + 65044480);    // end 130,072,576
    unsigned short* w1T   = (unsigned short*)(ws + 130080768);   // 256 rows, 1,179,648 B
    unsigned short* uw1T  = w1T + 256 * 2304;                    // 128 rows right after -> combined 384
    unsigned short* w2T   = uw1T + 128 * 2304;                   // 1,179,648 B
    float* scale1 = (float*)(w2T + 589824);                      // 384
    float* bias1  = scale1 + 384;                                // 384 (256 BN-fold + 128 ub1)
    float* scale2 = bias1 + 384;                                 // 256
    float* bias2  = scale2 + 256;                                // 256

    // single merged prep launch: weights pack + pads + depth-zero + scalars + feature pack
    prep_all<<<41089, 256, 0, stream>>>(
        w1, w2, uw1, w1T, w2T, uw1T,
        (unsigned int*)featP, (unsigned int*)h1P, out,
        b1, g1, be1, m1, v1, b2, g2, be2, m2, v2, ub1,
        scale1, bias1, scale2, bias2,
        features, featP);

    // merged conv1 (BN+ReLU, padded out) + fused uncertainty head; My=3, 2880 blocks.
    // <3>: verified optimum (r5: <4> thrashes L2 on the write-heavy pass).
    conv3x3_mfma<3><<<2880, 256, 0, stream>>>(
        featP, w1T, scale1, bias1, h1P, out + NPIX, uw2, ub2, 256, 1, 3);
    // conv2 + fused depth head: atomicAdd partial dots into out[0..NPIX); My=2, 1920 blocks.
    // <4>: this round's experiment — read-side-only working set at 16 waves/CU.
    conv3x3_mfma<4><<<1920, 256, 0, stream>>>(
        h1P, w2T, scale2, bias2, nullptr, out, w3, nullptr, 256, 0, 2);

    depth_transform<<<NPIX / 256, 256, 0, stream>>>(out, b3);
    median_kernel<<<BATCH * 64, 256, 0, stream>>>(out, bboxes, out + 2 * NPIX);
}

// Round 7
// 604.902 us; speedup vs baseline: 1.0472x; 1.0472x over previous
//
#include <hip/hip_runtime.h>
#include <hip/hip_bf16.h>

#define HH 96
#define WW 160
#define BATCH 8
#define NPIX (BATCH*HH*WW)   // 122880
#define CIN 256
#define IMG (HH*WW)          // 15360
#define PW 162               // padded width
#define PH 98                // padded height
#define PR (PH*PW)           // 15876 padded rows per image
#define PTOT (BATCH*PR)      // 127008 padded rows total

typedef short bf16x8 __attribute__((ext_vector_type(8)));
typedef float f32x4 __attribute__((ext_vector_type(4)));

__device__ __forceinline__ unsigned short f2bf(float f) {
    unsigned int u = __float_as_uint(f);
    u = (u + 0x7fffu + ((u >> 16) & 1u)) >> 16;   // RNE
    return (unsigned short)u;
}

__device__ __forceinline__ void gload16(const void* g, void* l) {
    __builtin_amdgcn_global_load_lds(
        (const __attribute__((address_space(1))) void*)g,
        (__attribute__((address_space(3))) void*)l,
        16, 0, 0);
}

// ---------------- merged prep: weights pack + pad zero + depth-acc zero + BN fold + feature pack ----
// Block roles by blockIdx.x:
//   [0, 5760)        : pack weights OIHW f32 -> [cout][pos][cin] bf16 (w1T | w2T | uw1T)
//   [5760, 9888)     : zero pad rows of featP/h1P (2 of the original 128-thread tasks per block)
//   [9888, 10368)    : zero depth accumulator out[0..NPIX)
//   10368            : BN fold scalars
//   [10369, 41089)   : NCHW f32 -> padded NHWC bf16
__global__ __launch_bounds__(256) void prep_all(
    const float* __restrict__ w1, const float* __restrict__ w2, const float* __restrict__ uw1,
    unsigned short* __restrict__ w1T, unsigned short* __restrict__ w2T, unsigned short* __restrict__ uw1T,
    unsigned int* __restrict__ featPu, unsigned int* __restrict__ h1Pu, float* __restrict__ outd,
    const float* __restrict__ b1, const float* __restrict__ g1, const float* __restrict__ be1,
    const float* __restrict__ m1, const float* __restrict__ v1,
    const float* __restrict__ b2, const float* __restrict__ g2, const float* __restrict__ be2,
    const float* __restrict__ m2, const float* __restrict__ v2,
    const float* __restrict__ ub1,
    float* __restrict__ scale1, float* __restrict__ bias1,
    float* __restrict__ scale2, float* __restrict__ bias2,
    const float* __restrict__ f, unsigned short* __restrict__ ft)
{
    __shared__ float tile[32][33];
    const int bid = blockIdx.x;
    const int t = threadIdx.x;

    if (bid < 5760) {
        const int S = 256 * 2304;       // 589824
        int i = bid * 256 + t;
        if (i < S) {
            int co = i / 2304, r = i % 2304, pos = r >> 8, ci = r & 255;
            w1T[i] = f2bf(w1[(co * 256 + ci) * 9 + pos]);
        } else if (i < 2 * S) {
            int j = i - S;
            int co = j / 2304, r = j % 2304, pos = r >> 8, ci = r & 255;
            w2T[j] = f2bf(w2[(co * 256 + ci) * 9 + pos]);
        } else {
            int j = i - 2 * S;          // < 128*2304
            int co = j / 2304, r = j % 2304, pos = r >> 8, ci = r & 255;
            uw1T[j] = f2bf(uw1[(co * 256 + ci) * 9 + pos]);
        }
    } else if (bid < 9888) {
        int k2 = (bid - 5760) * 2 + (t >> 7);   // 0..8255, two 128-lane tasks per block
        int lane = t & 127;
        unsigned int* buf = (k2 < 4128) ? featPu : h1Pu;
        int k = (k2 < 4128) ? k2 : (k2 - 4128);
        int img = k / 516, i = k % 516;
        int py, px;
        if (i < PW)            { py = 0;      px = i; }
        else if (i < 2 * PW)   { py = PH - 1; px = i - PW; }
        else { int q = i - 2 * PW; py = 1 + (q >> 1); px = (q & 1) ? (PW - 1) : 0; }
        size_t row = (size_t)img * PR + (size_t)py * PW + px;
        buf[row * 128 + lane] = 0;              // 512 B row of zeros
    } else if (bid < 10368) {
        outd[(size_t)(bid - 9888) * 256 + t] = 0.f;   // 480*256 = NPIX
    } else if (bid == 10368) {
        if (t < 256) {
            float s1 = g1[t] * rsqrtf(v1[t] + 1e-5f);
            scale1[t] = s1;
            bias1[t]  = (b1[t] - m1[t]) * s1 + be1[t];
            float s2 = g2[t] * rsqrtf(v2[t] + 1e-5f);
            scale2[t] = s2;
            bias2[t]  = (b2[t] - m2[t]) * s2 + be2[t];
            if (t < 128) { scale1[256 + t] = 1.0f; bias1[256 + t] = ub1[t]; }
        }
    } else {
        int id = bid - 10369;                   // 30720 pack blocks
        int x0 = (id % 5) * 32;                 // W/32 = 5
        int c0 = ((id / 5) % 8) * 32;           // C/32 = 8
        int by = id / 40;                       // B*H = 768
        int b = by / HH, y = by % HH;
        int tx = t & 31, tg = t >> 5;           // tg 0..7
        const float* src = f + (((size_t)(b * CIN + c0) * HH + y) * WW) + x0;
        #pragma unroll
        for (int i = 0; i < 4; ++i) {
            int cl = tg + i * 8;
            tile[cl][tx] = src[(size_t)cl * HH * WW + tx];
        }
        __syncthreads();
        size_t rbase = (size_t)b * PR + (size_t)(y + 1) * PW + (x0 + 1);
        #pragma unroll
        for (int i = 0; i < 4; ++i) {
            int xl = tg + i * 8;
            ft[(rbase + xl) * 256 + c0 + tx] = f2bf(tile[tx][xl]);
        }
    }
}

// ---------------- 3x3 conv, implicit GEMM: 128m x 256n blocks, 64x128 per wave ----------------
// LDS-port model (r1/r3/r5/r6 closed the sync + occupancy ladders at 46% MfmaUtil): per dx-step
// the old 64x64 wave issued 8 ds_read_b128 for 16 MFMA (ratio 2.0); the LDS read port (~4.3
// cyc/b128 sustained, CU-shared) caps MfmaUtil near the measured 46%. This version widens the
// wave tile to 64x128: 12 b128 -> 32 MFMA (ratio 2.67, +33% on the LDS-bound ceiling), and
// halves barriers per output pixel. acc[4][8] = 128 AGPR -> launch_bounds(256,2), 2 blocks/CU
// (r0 verified 2-block viability). Block covers 128m x 256n; spatial tiles 60/image.
// XCD swizzle: spatial s = xcd*60 + j/My -> one image per XCD.
// Row-wrap: 256-pixel tiles may wrap up to TWICE: offset = jj + 2*((x0+jj)/WW) (+7+dx);
// staged rows 272 >= max consumed 268.
// B swizzle (conflict-free): lane l stages row l>>2, quarter (l&3)^((l>>3)&3); read quarter
// quad^((row>>1)&3). 17 B-slots: wave w stages 4w..4w+3, wave 3 also slot 16.
// mode 0: conv2 + FUSED depth head: per-block partial dot with w3 (via uw2) over its 128
//         channels, one f32 atomicAdd per pixel into uout (2 contributors; commutative). My=2.
// mode 1: merged conv1 (padded bf16 out, m0<256) + fused uncertainty head (m0==256), My=3.
__global__ __launch_bounds__(256, 2) void conv3x3_mfma(
    const unsigned short* __restrict__ inP,
    const unsigned short* __restrict__ wT,
    const float* __restrict__ scale, const float* __restrict__ bias,
    unsigned short* __restrict__ outT,
    float* __restrict__ uout,
    const float* __restrict__ uw2, const float* __restrict__ ub2,
    int Cout, int mode, int My)
{
    __shared__ unsigned short Alds[3 * 128 * 32];   // 24576 B, [pos][slot][...]
    __shared__ unsigned short Blds[272 * 32];       // 17408 B, 17 slots
    __shared__ float usum[2][256];

    const int t = threadIdx.x;
    const int wave = t >> 6;
    const int l = t & 63;

    const int lid = blockIdx.x;
    const int xcd = lid & 7;
    const int j = lid >> 3;
    const int n0 = (xcd * 60 + j / My) * 256;
    const int m0 = (j % My) * 128;
    const bool is_unc = (mode == 1) && (m0 == 256);

    const int b0 = n0 / IMG;
    const int rem0 = n0 % IMG;
    const int y0 = rem0 / WW;
    const int x0 = rem0 % WW;
    const int r0 = b0 * PR + (y0 + 1) * PW + (x0 + 1);   // padded row of first output pixel

    const int lrow = l >> 2;
    const int lkq = (l & 3) ^ ((l >> 3) & 3);

    // A staging per-lane source bases (two 16-row slots per wave)
    const unsigned short* asrc0 = wT + (size_t)(m0 + wave * 32 + lrow) * 9 * 256 + lkq * 8;
    const unsigned short* asrc1 = asrc0 + (size_t)16 * 9 * 256;

    char* AldsB = (char*)Alds;
    char* BldsB = (char*)Blds;
    char* aldst = AldsB + wave * 2048;   // + dx*8192 (+1024 for second slot)

    const int wm = wave >> 1, wn = wave & 1;
    const int quad = l >> 4, lane16 = l & 15;
    const int aoff = lane16 * 64 + ((quad ^ ((lane16 >> 1) & 3)) << 4);

    // B fragment base tile-rows: pixel jj -> staged index jj + 2*wraps + 7 (+dx)
    int browbase[8];
    #pragma unroll
    for (int i = 0; i < 8; ++i) {
        int jj = wn * 128 + i * 16 + lane16;
        browbase[i] = jj + 2 * ((x0 + jj) / WW) + 7;
    }

    f32x4 acc[4][8];
    #pragma unroll
    for (int mt = 0; mt < 4; ++mt)
        #pragma unroll
        for (int nt = 0; nt < 8; ++nt)
            acc[mt][nt] = (f32x4){0.f, 0.f, 0.f, 0.f};

    for (int cc = 0; cc < 8; ++cc) {
        const int ccoff = cc * 32;
        for (int dyi = 0; dyi < 3; ++dyi) {
            __syncthreads();
            // ---- stage A: 3 pos-tiles (pos = dyi*3 + dx), 6 instr/wave
            const unsigned short* a0 = asrc0 + (dyi * 3) * 256 + ccoff;
            const unsigned short* a1 = asrc1 + (dyi * 3) * 256 + ccoff;
            #pragma unroll
            for (int dxp = 0; dxp < 3; ++dxp) {
                gload16(a0 + dxp * 256, aldst + dxp * 8192);
                gload16(a1 + dxp * 256, aldst + dxp * 8192 + 1024);
            }
            // ---- stage B: 272 padded rows [r0 + (dyi-1)*PW - 8, +272), 17 slots
            const ptrdiff_t rs = (ptrdiff_t)r0 + (ptrdiff_t)(dyi - 1) * PW - 8;
            const unsigned short* bs0 = inP + (rs + lrow) * 256 + ccoff + lkq * 8;
            #pragma unroll
            for (int k = 0; k < 4; ++k) {
                const int s = wave * 4 + k;
                gload16(bs0 + s * 4096, BldsB + s * 1024);
            }
            if (wave == 3) gload16(bs0 + 16 * 4096, BldsB + 16 * 1024);   // slot 16
            __syncthreads();
            // ---- compute: 3 dx shifts x 32 MFMA
            #pragma unroll
            for (int dx = 0; dx < 3; ++dx) {
                bf16x8 af[4], bfr[8];
                #pragma unroll
                for (int mt = 0; mt < 4; ++mt)
                    af[mt] = *(const bf16x8*)(AldsB + dx * 8192 + ((wm * 4 + mt) << 10) + aoff);
                #pragma unroll
                for (int i = 0; i < 8; ++i) {
                    int row = browbase[i] + dx;
                    int ba = (row << 6) + ((quad ^ ((row >> 1) & 3)) << 4);
                    bfr[i] = *(const bf16x8*)(BldsB + ba);
                }
                #pragma unroll
                for (int mt = 0; mt < 4; ++mt)
                    #pragma unroll
                    for (int nt = 0; nt < 8; ++nt)
                        acc[mt][nt] = __builtin_amdgcn_mfma_f32_16x16x32_bf16(
                            af[mt], bfr[nt], acc[mt][nt], 0, 0, 0);
            }
        }
    }

    if (is_unc) {
        // fused uncertainty head: relu(acc+ub1) dot uw2 over all 128 channels -> softplus
        const float* ub = bias + 256;
        float s[8] = {0.f, 0.f, 0.f, 0.f, 0.f, 0.f, 0.f, 0.f};
        #pragma unroll
        for (int mt = 0; mt < 4; ++mt) {
            const int mg = wm * 64 + mt * 16 + quad * 4;
            const float4 bi = *(const float4*)&ub[mg];
            const float4 uw = *(const float4*)&uw2[mg];
            #pragma unroll
            for (int nt = 0; nt < 8; ++nt) {
                s[nt] += fmaxf(acc[mt][nt][0] + bi.x, 0.f) * uw.x
                       + fmaxf(acc[mt][nt][1] + bi.y, 0.f) * uw.y
                       + fmaxf(acc[mt][nt][2] + bi.z, 0.f) * uw.z
                       + fmaxf(acc[mt][nt][3] + bi.w, 0.f) * uw.w;
            }
        }
        #pragma unroll
        for (int nt = 0; nt < 8; ++nt) {
            s[nt] += __shfl_xor(s[nt], 16);
            s[nt] += __shfl_xor(s[nt], 32);
        }
        if (quad == 0) {
            #pragma unroll
            for (int nt = 0; nt < 8; ++nt)
                usum[wm][wn * 128 + nt * 16 + lane16] = s[nt];
        }
        __syncthreads();
        {
            float x = usum[0][t] + usum[1][t] + ub2[0];
            uout[n0 + t] = fmaxf(x, 0.f) + log1pf(expf(-fabsf(x)));
        }
        return;
    }

    if (mode == 0) {
        // fused depth head: partial dot of relu(acc*scale+bias) with w3 (in uw2) over this
        // block's 128 channels; reduce quad via shfl, wm via LDS, one atomicAdd per pixel.
        float s[8] = {0.f, 0.f, 0.f, 0.f, 0.f, 0.f, 0.f, 0.f};
        #pragma unroll
        for (int mt = 0; mt < 4; ++mt) {
            const int mg = m0 + wm * 64 + mt * 16 + quad * 4;
            const float4 sc = *(const float4*)&scale[mg];
            const float4 bi = *(const float4*)&bias[mg];
            const float4 w  = *(const float4*)&uw2[mg];
            #pragma unroll
            for (int nt = 0; nt < 8; ++nt) {
                s[nt] += fmaxf(acc[mt][nt][0] * sc.x + bi.x, 0.f) * w.x
                       + fmaxf(acc[mt][nt][1] * sc.y + bi.y, 0.f) * w.y
                       + fmaxf(acc[mt][nt][2] * sc.z + bi.z, 0.f) * w.z
                       + fmaxf(acc[mt][nt][3] * sc.w + bi.w, 0.f) * w.w;
            }
        }
        #pragma unroll
        for (int nt = 0; nt < 8; ++nt) {
            s[nt] += __shfl_xor(s[nt], 16);
            s[nt] += __shfl_xor(s[nt], 32);
        }
        if (quad == 0) {
            #pragma unroll
            for (int nt = 0; nt < 8; ++nt)
                usum[wm][wn * 128 + nt * 16 + lane16] = s[nt];
        }
        __syncthreads();
        atomicAdd(&uout[n0 + t], usum[0][t] + usum[1][t]);
        return;
    }

    // mode 1 conv output: y = relu(acc*scale + bias) -> bf16 padded rows
    size_t obase[8];
    #pragma unroll
    for (int nt = 0; nt < 8; ++nt) {
        int n = n0 + wn * 128 + nt * 16 + lane16;
        int b = n / IMG, rem = n % IMG, yy = rem / WW, xx = rem % WW;
        obase[nt] = ((size_t)(b * PH + yy + 1) * PW + (xx + 1)) * 256;
    }
    #pragma unroll
    for (int mt = 0; mt < 4; ++mt) {
        const int mg = m0 + wm * 64 + mt * 16 + quad * 4;
        const float4 sc = *(const float4*)&scale[mg];
        const float4 bi = *(const float4*)&bias[mg];
        #pragma unroll
        for (int nt = 0; nt < 8; ++nt) {
            ushort4 pk;
            pk.x = f2bf(fmaxf(acc[mt][nt][0] * sc.x + bi.x, 0.f));
            pk.y = f2bf(fmaxf(acc[mt][nt][1] * sc.y + bi.y, 0.f));
            pk.z = f2bf(fmaxf(acc[mt][nt][2] * sc.z + bi.z, 0.f));
            pk.w = f2bf(fmaxf(acc[mt][nt][3] * sc.w + bi.w, 0.f));
            *(ushort4*)&outT[obase[nt] + mg] = pk;
        }
    }
}

// ---------------- finalize depth: x -> 1/(0.01 + 9.99*sigmoid(x + b3)) in-place ----------------
__global__ __launch_bounds__(256) void depth_transform(
    float* __restrict__ out, const float* __restrict__ b3)
{
    int i = blockIdx.x * 256 + threadIdx.x;    // 480 * 256 = NPIX exactly
    float x = out[i] + b3[0];
    float sig = 1.f / (1.f + expf(-x));
    out[i] = 1.f / (0.01f + 9.99f * sig);
}

// ---------------- per-box lower-median via 4-pass radix select on float bits ----------------
__global__ __launch_bounds__(256) void median_kernel(
    const float* __restrict__ depth, const int* __restrict__ bboxes, float* __restrict__ obj)
{
    const int bi = blockIdx.x;          // b*64 + box
    const int b = bi >> 6;
    const int* bb = bboxes + (size_t)bi * 4;
    int x1 = max(bb[0], 0), y1 = max(bb[1], 0);
    int x2 = min(bb[2], WW), y2 = min(bb[3], HH);
    int w = x2 - x1, h = y2 - y1;
    if (w <= 0 || h <= 0) {
        if (threadIdx.x == 0) obj[bi] = 0.f;
        return;
    }
    const int wh = w * h;
    int tgt = (wh - 1) >> 1;            // lower median index
    const float* dbase = depth + (size_t)b * HH * WW;

    __shared__ unsigned int hist[256];
    __shared__ unsigned int sel_prefix, sel_target;
    unsigned int prefix = 0;

    for (int pass = 0; pass < 4; ++pass) {
        const int shift = 24 - 8 * pass;
        hist[threadIdx.x] = 0;
        __syncthreads();
        const unsigned int mask_high = (pass == 0) ? 0u : (0xFFFFFFFFu << (shift + 8));
        for (int idx = threadIdx.x; idx < wh; idx += 256) {
            int yy = y1 + idx / w, xx = x1 + idx % w;
            unsigned int uu = __float_as_uint(dbase[yy * WW + xx]);
            if ((uu & mask_high) == (prefix & mask_high))
                atomicAdd(&hist[(uu >> shift) & 255], 1u);
        }
        __syncthreads();
        if (threadIdx.x == 0) {
            unsigned int cum = 0;
            for (int bin = 0; bin < 256; ++bin) {
                unsigned int c = hist[bin];
                if (cum + c > (unsigned int)tgt) {
                    sel_target = (unsigned int)tgt - cum;
                    sel_prefix = prefix | ((unsigned int)bin << shift);
                    break;
                }
                cum += c;
            }
        }
        __syncthreads();
        prefix = sel_prefix;
        tgt = (int)sel_target;
    }
    if (threadIdx.x == 0) obj[bi] = __uint_as_float(prefix);
}

extern "C" void kernel_launch(void* const* d_in, const int* in_sizes, int n_in,
                              void* d_out, int out_size, void* d_ws, size_t ws_size,
                              hipStream_t stream) {
    const float* features = (const float*)d_in[0];
    const int*   bboxes   = (const int*)d_in[1];
    const float* w1  = (const float*)d_in[2];
    const float* b1  = (const float*)d_in[3];
    const float* g1  = (const float*)d_in[4];
    const float* be1 = (const float*)d_in[5];
    const float* m1  = (const float*)d_in[6];
    const float* v1  = (const float*)d_in[7];
    const float* w2  = (const float*)d_in[8];
    const float* b2  = (const float*)d_in[9];
    const float* g2  = (const float*)d_in[10];
    const float* be2 = (const float*)d_in[11];
    const float* m2  = (const float*)d_in[12];
    const float* v2  = (const float*)d_in[13];
    const float* w3  = (const float*)d_in[14];
    const float* b3  = (const float*)d_in[15];
    const float* uw1 = (const float*)d_in[16];
    const float* ub1 = (const float*)d_in[17];
    const float* uw2 = (const float*)d_in[18];
    const float* ub2 = (const float*)d_in[19];
    float* out = (float*)d_out;

    char* ws = (char*)d_ws;
    // layout (bytes). Padded buffers have 8 KB read-slack gaps on both sides.
    unsigned short* featP = (unsigned short*)(ws + 8192);        // 65,028,096 -> end 65,036,288
    unsigned short* h1P   = (unsigned short*)(ws + 65044480);    // end 130,072,576
    unsigned short* w1T   = (unsigned short*)(ws + 130080768);   // 256 rows, 1,179,648 B
    unsigned short* uw1T  = w1T + 256 * 2304;                    // 128 rows right after -> combined 384
    unsigned short* w2T   = uw1T + 128 * 2304;                   // 1,179,648 B
    float* scale1 = (float*)(w2T + 589824);                      // 384
    float* bias1  = scale1 + 384;                                // 384 (256 BN-fold + 128 ub1)
    float* scale2 = bias1 + 384;                                 // 256
    float* bias2  = scale2 + 256;                                // 256

    // single merged prep launch: weights pack + pads + depth-zero + scalars + feature pack
    prep_all<<<41089, 256, 0, stream>>>(
        w1, w2, uw1, w1T, w2T, uw1T,
        (unsigned int*)featP, (unsigned int*)h1P, out,
        b1, g1, be1, m1, v1, b2, g2, be2, m2, v2, ub1,
        scale1, bias1, scale2, bias2,
        features, featP);

    // merged conv1 (BN+ReLU, padded out) + fused uncertainty head; My=3, 1440 blocks (256n tiles)
    conv3x3_mfma<<<1440, 256, 0, stream>>>(
        featP, w1T, scale1, bias1, h1P, out + NPIX, uw2, ub2, 256, 1, 3);
    // conv2 + fused depth head: atomicAdd partial dots into out[0..NPIX); My=2, 960 blocks
    conv3x3_mfma<<<960, 256, 0, stream>>>(
        h1P, w2T, scale2, bias2, nullptr, out, w3, nullptr, 256, 0, 2);

    depth_transform<<<NPIX / 256, 256, 0, stream>>>(out, b3);
    median_kernel<<<BATCH * 64, 256, 0, stream>>>(out, bboxes, out + 2 * NPIX);
}

// Round 8
// 602.275 us; speedup vs baseline: 1.0518x; 1.0044x over previous
//
#include <hip/hip_runtime.h>
#include <hip/hip_bf16.h>

#define HH 96
#define WW 160
#define BATCH 8
#define NPIX (BATCH*HH*WW)   // 122880
#define CIN 256
#define IMG (HH*WW)          // 15360
#define PW 162               // padded width
#define PH 98                // padded height
#define PR (PH*PW)           // 15876 padded rows per image
#define PTOT (BATCH*PR)      // 127008 padded rows total

typedef short bf16x8 __attribute__((ext_vector_type(8)));
typedef float f32x4 __attribute__((ext_vector_type(4)));

__device__ __forceinline__ unsigned short f2bf(float f) {
    unsigned int u = __float_as_uint(f);
    u = (u + 0x7fffu + ((u >> 16) & 1u)) >> 16;   // RNE
    return (unsigned short)u;
}

__device__ __forceinline__ void gload16(const void* g, void* l) {
    __builtin_amdgcn_global_load_lds(
        (const __attribute__((address_space(1))) void*)g,
        (__attribute__((address_space(3))) void*)l,
        16, 0, 0);
}

// ---------------- merged prep: weights pack + pad zero + depth-acc zero + BN fold + feature pack ----
// Block roles by blockIdx.x:
//   [0, 5760)        : pack weights OIHW f32 -> [cout][pos][cin] bf16 (w1T | w2T | uw1T)
//   [5760, 9888)     : zero pad rows of featP/h1P (2 of the original 128-thread tasks per block)
//   [9888, 10368)    : zero depth accumulator out[0..NPIX)
//   10368            : BN fold scalars
//   [10369, 41089)   : NCHW f32 -> padded NHWC bf16
__global__ __launch_bounds__(256) void prep_all(
    const float* __restrict__ w1, const float* __restrict__ w2, const float* __restrict__ uw1,
    unsigned short* __restrict__ w1T, unsigned short* __restrict__ w2T, unsigned short* __restrict__ uw1T,
    unsigned int* __restrict__ featPu, unsigned int* __restrict__ h1Pu, float* __restrict__ outd,
    const float* __restrict__ b1, const float* __restrict__ g1, const float* __restrict__ be1,
    const float* __restrict__ m1, const float* __restrict__ v1,
    const float* __restrict__ b2, const float* __restrict__ g2, const float* __restrict__ be2,
    const float* __restrict__ m2, const float* __restrict__ v2,
    const float* __restrict__ ub1,
    float* __restrict__ scale1, float* __restrict__ bias1,
    float* __restrict__ scale2, float* __restrict__ bias2,
    const float* __restrict__ f, unsigned short* __restrict__ ft)
{
    __shared__ float tile[32][33];
    const int bid = blockIdx.x;
    const int t = threadIdx.x;

    if (bid < 5760) {
        const int S = 256 * 2304;       // 589824
        int i = bid * 256 + t;
        if (i < S) {
            int co = i / 2304, r = i % 2304, pos = r >> 8, ci = r & 255;
            w1T[i] = f2bf(w1[(co * 256 + ci) * 9 + pos]);
        } else if (i < 2 * S) {
            int j = i - S;
            int co = j / 2304, r = j % 2304, pos = r >> 8, ci = r & 255;
            w2T[j] = f2bf(w2[(co * 256 + ci) * 9 + pos]);
        } else {
            int j = i - 2 * S;          // < 128*2304
            int co = j / 2304, r = j % 2304, pos = r >> 8, ci = r & 255;
            uw1T[j] = f2bf(uw1[(co * 256 + ci) * 9 + pos]);
        }
    } else if (bid < 9888) {
        int k2 = (bid - 5760) * 2 + (t >> 7);   // 0..8255, two 128-lane tasks per block
        int lane = t & 127;
        unsigned int* buf = (k2 < 4128) ? featPu : h1Pu;
        int k = (k2 < 4128) ? k2 : (k2 - 4128);
        int img = k / 516, i = k % 516;
        int py, px;
        if (i < PW)            { py = 0;      px = i; }
        else if (i < 2 * PW)   { py = PH - 1; px = i - PW; }
        else { int q = i - 2 * PW; py = 1 + (q >> 1); px = (q & 1) ? (PW - 1) : 0; }
        size_t row = (size_t)img * PR + (size_t)py * PW + px;
        buf[row * 128 + lane] = 0;              // 512 B row of zeros
    } else if (bid < 10368) {
        outd[(size_t)(bid - 9888) * 256 + t] = 0.f;   // 480*256 = NPIX
    } else if (bid == 10368) {
        if (t < 256) {
            float s1 = g1[t] * rsqrtf(v1[t] + 1e-5f);
            scale1[t] = s1;
            bias1[t]  = (b1[t] - m1[t]) * s1 + be1[t];
            float s2 = g2[t] * rsqrtf(v2[t] + 1e-5f);
            scale2[t] = s2;
            bias2[t]  = (b2[t] - m2[t]) * s2 + be2[t];
            if (t < 128) { scale1[256 + t] = 1.0f; bias1[256 + t] = ub1[t]; }
        }
    } else {
        int id = bid - 10369;                   // 30720 pack blocks
        int x0 = (id % 5) * 32;                 // W/32 = 5
        int c0 = ((id / 5) % 8) * 32;           // C/32 = 8
        int by = id / 40;                       // B*H = 768
        int b = by / HH, y = by % HH;
        int tx = t & 31, tg = t >> 5;           // tg 0..7
        const float* src = f + (((size_t)(b * CIN + c0) * HH + y) * WW) + x0;
        #pragma unroll
        for (int i = 0; i < 4; ++i) {
            int cl = tg + i * 8;
            tile[cl][tx] = src[(size_t)cl * HH * WW + tx];
        }
        __syncthreads();
        size_t rbase = (size_t)b * PR + (size_t)(y + 1) * PW + (x0 + 1);
        #pragma unroll
        for (int i = 0; i < 4; ++i) {
            int xl = tg + i * 8;
            ft[(rbase + xl) * 256 + c0 + tx] = f2bf(tile[tx][xl]);
        }
    }
}

// ---------------- 3x3 conv, implicit GEMM: 128m x 256n blocks, 64x128/wave, 3-phase pipeline ----
// r7 post-mortem: MfmaUtil stuck 47% with MFMA 50% / LDS-port 55% / VALU 20% of wall — no pipe
// saturated; the gap is load latency exposed at the per-iteration barrier drain (2 blocks/CU,
// register-capped, can't add TLP). Fix = counted-vmcnt phase-split (T3+T4+T5):
// each K-step (cc,dyi) = 3 phases [vmcnt(N) -> s_barrier -> issue stages -> compute dx=d].
// B double-buffered (2x17KB): B(t+1) issued at P0(t), waited at P0(t+1) (3 phases in flight).
// A single 3-slot buffer, rotating overwrite: slot d restaged the phase AFTER its last read
// (slot2 at P0(t) for t's own P2; slot0 at P1(t) and slot1 at P2(t) for t+1), waited 2 phases
// later. FIFO-derived vmcnt leave-counts (waves0-2/wave3): P0 2/2, P1 6/7, P2 6/7;
// tail t=23: 2, 2, 0 (issues skipped). Slot-safety: every overwrite is issued after the
// barrier that ends the phase which last read that slot; every read is vmcnt-covered.
// s_setprio(1) around each 32-MFMA cluster (T5 — pays only with phase role-split, m218b).
// LDS = A 24K + B 34K + usum 2K = 60KB -> 2 blocks/CU.
// XCD swizzle: spatial s = xcd*60 + j/My -> one image per XCD.
// Row-wrap: 256-pixel tiles wrap up to twice: offset = jj + 2*((x0+jj)/WW) (+7+dx).
// B swizzle (conflict-free): lane l stages row l>>2, quarter (l&3)^((l>>3)&3); read quarter
// quad^((row>>1)&3). 17 B-slots/buffer: wave w stages 4w..4w+3, wave 3 also slot 16.
// mode 0: conv2 + FUSED depth head (partial dot with w3 via uw2, atomicAdd into uout). My=2.
// mode 1: merged conv1 (padded bf16 out, m0<256) + fused uncertainty head (m0==256), My=3.
__global__ __launch_bounds__(256, 2) void conv3x3_mfma(
    const unsigned short* __restrict__ inP,
    const unsigned short* __restrict__ wT,
    const float* __restrict__ scale, const float* __restrict__ bias,
    unsigned short* __restrict__ outT,
    float* __restrict__ uout,
    const float* __restrict__ uw2, const float* __restrict__ ub2,
    int Cout, int mode, int My)
{
    __shared__ unsigned short Alds[3 * 128 * 32];   // 24576 B, 3 pos slots
    __shared__ unsigned short Blds[2][272 * 32];    // 2 x 17408 B, 17 slots each
    __shared__ float usum[2][256];

    const int t = threadIdx.x;
    const int wave = t >> 6;
    const int l = t & 63;

    const int lid = blockIdx.x;
    const int xcd = lid & 7;
    const int j = lid >> 3;
    const int n0 = (xcd * 60 + j / My) * 256;
    const int m0 = (j % My) * 128;
    const bool is_unc = (mode == 1) && (m0 == 256);

    const int b0 = n0 / IMG;
    const int rem0 = n0 % IMG;
    const int y0 = rem0 / WW;
    const int x0 = rem0 % WW;
    const int r0 = b0 * PR + (y0 + 1) * PW + (x0 + 1);   // padded row of first output pixel

    const int lrow = l >> 2;
    const int lkq = (l & 3) ^ ((l >> 3) & 3);

    // A staging per-lane source bases (two 16-row slots per wave)
    const unsigned short* asrc0 = wT + (size_t)(m0 + wave * 32 + lrow) * 9 * 256 + lkq * 8;
    const unsigned short* asrc1 = asrc0 + (size_t)16 * 9 * 256;

    char* AldsB = (char*)Alds;
    char* BldsB = (char*)Blds;
    char* aldst = AldsB + wave * 2048;

    const int wm = wave >> 1, wn = wave & 1;
    const int quad = l >> 4, lane16 = l & 15;
    const int aoff = lane16 * 64 + ((quad ^ ((lane16 >> 1) & 3)) << 4);

    // B fragment base tile-rows: pixel jj -> staged index jj + 2*wraps + 7 (+dx)
    int browbase[8];
    #pragma unroll
    for (int i = 0; i < 8; ++i) {
        int jj = wn * 128 + i * 16 + lane16;
        browbase[i] = jj + 2 * ((x0 + jj) / WW) + 7;
    }

    f32x4 acc[4][8];
    #pragma unroll
    for (int mt = 0; mt < 4; ++mt)
        #pragma unroll
        for (int nt = 0; nt < 8; ++nt)
            acc[mt][nt] = (f32x4){0.f, 0.f, 0.f, 0.f};

    // stage B rows [r0 + (dyi-1)*PW - 8, +272) of cc-chunk into buffer sel (4-5 gloads/wave)
    auto STAGE_B = [&](int ccoff, int dyi, int sel) {
        const ptrdiff_t rs = (ptrdiff_t)r0 + (ptrdiff_t)(dyi - 1) * PW - 8;
        const unsigned short* bs0 = inP + (rs + lrow) * 256 + ccoff + lkq * 8;
        char* bd = BldsB + sel * 17408;
        #pragma unroll
        for (int k = 0; k < 4; ++k) {
            const int s = wave * 4 + k;
            gload16(bs0 + s * 4096, bd + s * 1024);
        }
        if (wave == 3) gload16(bs0 + 16 * 4096, bd + 16 * 1024);
    };
    // stage one A pos-tile into slot (2 gloads/wave)
    auto STAGE_A = [&](int ccoff, int pos, int slot) {
        const unsigned short* a0 = asrc0 + pos * 256 + ccoff;
        const unsigned short* a1 = asrc1 + pos * 256 + ccoff;
        gload16(a0, aldst + slot * 8192);
        gload16(a1, aldst + slot * 8192 + 1024);
    };

    // prologue: B(0) -> buf0, A(0)[0] -> slot0, A(0)[1] -> slot1; full drain.
    STAGE_B(0, 0, 0);
    STAGE_A(0, 0, 0);
    STAGE_A(0, 1, 1);
    asm volatile("s_waitcnt vmcnt(0)" ::: "memory");
    __builtin_amdgcn_s_barrier();
    asm volatile("" ::: "memory");

    #define COMPUTE_PHASE(d)                                                          \
    {                                                                                 \
        __builtin_amdgcn_s_setprio(1);                                                \
        bf16x8 af[4], bfr[8];                                                         \
        _Pragma("unroll")                                                             \
        for (int mt = 0; mt < 4; ++mt)                                                \
            af[mt] = *(const bf16x8*)(AldsB + (d) * 8192 + ((wm * 4 + mt) << 10) + aoff); \
        _Pragma("unroll")                                                             \
        for (int i = 0; i < 8; ++i) {                                                 \
            int row = browbase[i] + (d);                                              \
            int ba = (row << 6) + ((quad ^ ((row >> 1) & 3)) << 4);                   \
            bfr[i] = *(const bf16x8*)(Bb + ba);                                       \
        }                                                                             \
        _Pragma("unroll")                                                             \
        for (int mt = 0; mt < 4; ++mt)                                                \
            _Pragma("unroll")                                                         \
            for (int nt = 0; nt < 8; ++nt)                                            \
                acc[mt][nt] = __builtin_amdgcn_mfma_f32_16x16x32_bf16(                \
                    af[mt], bfr[nt], acc[mt][nt], 0, 0, 0);                           \
        __builtin_amdgcn_s_setprio(0);                                                \
    }

    for (int it = 0; it < 24; ++it) {
        const int dyi = it - (it / 3) * 3;
        const int ccoff = (it / 3) * 32;
        const int itn = it + 1;
        const int dyin = itn - (itn / 3) * 3;
        const int ccoffn = (itn / 3) * 32;
        const char* Bb = BldsB + (it & 1) * 17408;

        // ---------- phase 0 (dx=0): reads A slot0 + B(t) ----------
        asm volatile("s_waitcnt vmcnt(2)" ::: "memory");      // drain B(t) + A(t)[0]
        __builtin_amdgcn_sched_barrier(0);
        __builtin_amdgcn_s_barrier();
        asm volatile("" ::: "memory");
        STAGE_A(ccoff, dyi * 3 + 2, 2);                       // A(t)[2] -> slot2 (read P2 of t)
        if (it < 23) STAGE_B(ccoffn, dyin, itn & 1);          // B(t+1)
        COMPUTE_PHASE(0);

        // ---------- phase 1 (dx=1): reads A slot1 + B(t) ----------
        if (it < 23) {
            if (wave == 3) { asm volatile("s_waitcnt vmcnt(7)" ::: "memory"); }
            else           { asm volatile("s_waitcnt vmcnt(6)" ::: "memory"); }
        } else {
            asm volatile("s_waitcnt vmcnt(2)" ::: "memory");
        }
        __builtin_amdgcn_sched_barrier(0);
        __builtin_amdgcn_s_barrier();
        asm volatile("" ::: "memory");
        if (it < 23) STAGE_A(ccoffn, dyin * 3 + 0, 0);        // A(t+1)[0] -> slot0
        COMPUTE_PHASE(1);

        // ---------- phase 2 (dx=2): reads A slot2 + B(t) ----------
        if (it < 23) {
            if (wave == 3) { asm volatile("s_waitcnt vmcnt(7)" ::: "memory"); }
            else           { asm volatile("s_waitcnt vmcnt(6)" ::: "memory"); }
        } else {
            asm volatile("s_waitcnt vmcnt(0)" ::: "memory");
        }
        __builtin_amdgcn_sched_barrier(0);
        __builtin_amdgcn_s_barrier();
        asm volatile("" ::: "memory");
        if (it < 23) STAGE_A(ccoffn, dyin * 3 + 1, 1);        // A(t+1)[1] -> slot1
        COMPUTE_PHASE(2);
    }
    #undef COMPUTE_PHASE

    if (is_unc) {
        // fused uncertainty head: relu(acc+ub1) dot uw2 over all 128 channels -> softplus
        const float* ub = bias + 256;
        float s[8] = {0.f, 0.f, 0.f, 0.f, 0.f, 0.f, 0.f, 0.f};
        #pragma unroll
        for (int mt = 0; mt < 4; ++mt) {
            const int mg = wm * 64 + mt * 16 + quad * 4;
            const float4 bi = *(const float4*)&ub[mg];
            const float4 uw = *(const float4*)&uw2[mg];
            #pragma unroll
            for (int nt = 0; nt < 8; ++nt) {
                s[nt] += fmaxf(acc[mt][nt][0] + bi.x, 0.f) * uw.x
                       + fmaxf(acc[mt][nt][1] + bi.y, 0.f) * uw.y
                       + fmaxf(acc[mt][nt][2] + bi.z, 0.f) * uw.z
                       + fmaxf(acc[mt][nt][3] + bi.w, 0.f) * uw.w;
            }
        }
        #pragma unroll
        for (int nt = 0; nt < 8; ++nt) {
            s[nt] += __shfl_xor(s[nt], 16);
            s[nt] += __shfl_xor(s[nt], 32);
        }
        __syncthreads();
        if (quad == 0) {
            #pragma unroll
            for (int nt = 0; nt < 8; ++nt)
                usum[wm][wn * 128 + nt * 16 + lane16] = s[nt];
        }
        __syncthreads();
        {
            float x = usum[0][t] + usum[1][t] + ub2[0];
            uout[n0 + t] = fmaxf(x, 0.f) + log1pf(expf(-fabsf(x)));
        }
        return;
    }

    if (mode == 0) {
        // fused depth head: partial dot of relu(acc*scale+bias) with w3 (in uw2) over this
        // block's 128 channels; reduce quad via shfl, wm via LDS, one atomicAdd per pixel.
        float s[8] = {0.f, 0.f, 0.f, 0.f, 0.f, 0.f, 0.f, 0.f};
        #pragma unroll
        for (int mt = 0; mt < 4; ++mt) {
            const int mg = m0 + wm * 64 + mt * 16 + quad * 4;
            const float4 sc = *(const float4*)&scale[mg];
            const float4 bi = *(const float4*)&bias[mg];
            const float4 w  = *(const float4*)&uw2[mg];
            #pragma unroll
            for (int nt = 0; nt < 8; ++nt) {
                s[nt] += fmaxf(acc[mt][nt][0] * sc.x + bi.x, 0.f) * w.x
                       + fmaxf(acc[mt][nt][1] * sc.y + bi.y, 0.f) * w.y
                       + fmaxf(acc[mt][nt][2] * sc.z + bi.z, 0.f) * w.z
                       + fmaxf(acc[mt][nt][3] * sc.w + bi.w, 0.f) * w.w;
            }
        }
        #pragma unroll
        for (int nt = 0; nt < 8; ++nt) {
            s[nt] += __shfl_xor(s[nt], 16);
            s[nt] += __shfl_xor(s[nt], 32);
        }
        __syncthreads();
        if (quad == 0) {
            #pragma unroll
            for (int nt = 0; nt < 8; ++nt)
                usum[wm][wn * 128 + nt * 16 + lane16] = s[nt];
        }
        __syncthreads();
        atomicAdd(&uout[n0 + t], usum[0][t] + usum[1][t]);
        return;
    }

    // mode 1 conv output: y = relu(acc*scale + bias) -> bf16 padded rows
    size_t obase[8];
    #pragma unroll
    for (int nt = 0; nt < 8; ++nt) {
        int n = n0 + wn * 128 + nt * 16 + lane16;
        int b = n / IMG, rem = n % IMG, yy = rem / WW, xx = rem % WW;
        obase[nt] = ((size_t)(b * PH + yy + 1) * PW + (xx + 1)) * 256;
    }
    #pragma unroll
    for (int mt = 0; mt < 4; ++mt) {
        const int mg = m0 + wm * 64 + mt * 16 + quad * 4;
        const float4 sc = *(const float4*)&scale[mg];
        const float4 bi = *(const float4*)&bias[mg];
        #pragma unroll
        for (int nt = 0; nt < 8; ++nt) {
            ushort4 pk;
            pk.x = f2bf(fmaxf(acc[mt][nt][0] * sc.x + bi.x, 0.f));
            pk.y = f2bf(fmaxf(acc[mt][nt][1] * sc.y + bi.y, 0.f));
            pk.z = f2bf(fmaxf(acc[mt][nt][2] * sc.z + bi.z, 0.f));
            pk.w = f2bf(fmaxf(acc[mt][nt][3] * sc.w + bi.w, 0.f));
            *(ushort4*)&outT[obase[nt] + mg] = pk;
        }
    }
}

// ---------------- finalize depth: x -> 1/(0.01 + 9.99*sigmoid(x + b3)) in-place ----------------
__global__ __launch_bounds__(256) void depth_transform(
    float* __restrict__ out, const float* __restrict__ b3)
{
    int i = blockIdx.x * 256 + threadIdx.x;    // 480 * 256 = NPIX exactly
    float x = out[i] + b3[0];
    float sig = 1.f / (1.f + expf(-x));
    out[i] = 1.f / (0.01f + 9.99f * sig);
}

// ---------------- per-box lower-median via 4-pass radix select on float bits ----------------
__global__ __launch_bounds__(256) void median_kernel(
    const float* __restrict__ depth, const int* __restrict__ bboxes, float* __restrict__ obj)
{
    const int bi = blockIdx.x;          // b*64 + box
    const int b = bi >> 6;
    const int* bb = bboxes + (size_t)bi * 4;
    int x1 = max(bb[0], 0), y1 = max(bb[1], 0);
    int x2 = min(bb[2], WW), y2 = min(bb[3], HH);
    int w = x2 - x1, h = y2 - y1;
    if (w <= 0 || h <= 0) {
        if (threadIdx.x == 0) obj[bi] = 0.f;
        return;
    }
    const int wh = w * h;
    int tgt = (wh - 1) >> 1;            // lower median index
    const float* dbase = depth + (size_t)b * HH * WW;

    __shared__ unsigned int hist[256];
    __shared__ unsigned int sel_prefix, sel_target;
    unsigned int prefix = 0;

    for (int pass = 0; pass < 4; ++pass) {
        const int shift = 24 - 8 * pass;
        hist[threadIdx.x] = 0;
        __syncthreads();
        const unsigned int mask_high = (pass == 0) ? 0u : (0xFFFFFFFFu << (shift + 8));
        for (int idx = threadIdx.x; idx < wh; idx += 256) {
            int yy = y1 + idx / w, xx = x1 + idx % w;
            unsigned int uu = __float_as_uint(dbase[yy * WW + xx]);
            if ((uu & mask_high) == (prefix & mask_high))
                atomicAdd(&hist[(uu >> shift) & 255], 1u);
        }
        __syncthreads();
        if (threadIdx.x == 0) {
            unsigned int cum = 0;
            for (int bin = 0; bin < 256; ++bin) {
                unsigned int c = hist[bin];
                if (cum + c > (unsigned int)tgt) {
                    sel_target = (unsigned int)tgt - cum;
                    sel_prefix = prefix | ((unsigned int)bin << shift);
                    break;
                }
                cum += c;
            }
        }
        __syncthreads();
        prefix = sel_prefix;
        tgt = (int)sel_target;
    }
    if (threadIdx.x == 0) obj[bi] = __uint_as_float(prefix);
}

extern "C" void kernel_launch(void* const* d_in, const int* in_sizes, int n_in,
                              void* d_out, int out_size, void* d_ws, size_t ws_size,
                              hipStream_t stream) {
    const float* features = (const float*)d_in[0];
    const int*   bboxes   = (const int*)d_in[1];
    const float* w1  = (const float*)d_in[2];
    const float* b1  = (const float*)d_in[3];
    const float* g1  = (const float*)d_in[4];
    const float* be1 = (const float*)d_in[5];
    const float* m1  = (const float*)d_in[6];
    const float* v1  = (const float*)d_in[7];
    const float* w2  = (const float*)d_in[8];
    const float* b2  = (const float*)d_in[9];
    const float* g2  = (const float*)d_in[10];
    const float* be2 = (const float*)d_in[11];
    const float* m2  = (const float*)d_in[12];
    const float* v2  = (const float*)d_in[13];
    const float* w3  = (const float*)d_in[14];
    const float* b3  = (const float*)d_in[15];
    const float* uw1 = (const float*)d_in[16];
    const float* ub1 = (const float*)d_in[17];
    const float* uw2 = (const float*)d_in[18];
    const float* ub2 = (const float*)d_in[19];
    float* out = (float*)d_out;

    char* ws = (char*)d_ws;
    // layout (bytes). Padded buffers have 8 KB read-slack gaps on both sides.
    unsigned short* featP = (unsigned short*)(ws + 8192);        // 65,028,096 -> end 65,036,288
    unsigned short* h1P   = (unsigned short*)(ws + 65044480);    // end 130,072,576
    unsigned short* w1T   = (unsigned short*)(ws + 130080768);   // 256 rows, 1,179,648 B
    unsigned short* uw1T  = w1T + 256 * 2304;                    // 128 rows right after -> combined 384
    unsigned short* w2T   = uw1T + 128 * 2304;                   // 1,179,648 B
    float* scale1 = (float*)(w2T + 589824);                      // 384
    float* bias1  = scale1 + 384;                                // 384 (256 BN-fold + 128 ub1)
    float* scale2 = bias1 + 384;                                 // 256
    float* bias2  = scale2 + 256;                                // 256

    // single merged prep launch: weights pack + pads + depth-zero + scalars + feature pack
    prep_all<<<41089, 256, 0, stream>>>(
        w1, w2, uw1, w1T, w2T, uw1T,
        (unsigned int*)featP, (unsigned int*)h1P, out,
        b1, g1, be1, m1, v1, b2, g2, be2, m2, v2, ub1,
        scale1, bias1, scale2, bias2,
        features, featP);

    // merged conv1 (BN+ReLU, padded out) + fused uncertainty head; My=3, 1440 blocks (256n tiles)
    conv3x3_mfma<<<1440, 256, 0, stream>>>(
        featP, w1T, scale1, bias1, h1P, out + NPIX, uw2, ub2, 256, 1, 3);
    // conv2 + fused depth head: atomicAdd partial dots into out[0..NPIX); My=2, 960 blocks
    conv3x3_mfma<<<960, 256, 0, stream>>>(
        h1P, w2T, scale2, bias2, nullptr, out, w3, nullptr, 256, 0, 2);

    depth_transform<<<NPIX / 256, 256, 0, stream>>>(out, b3);
    median_kernel<<<BATCH * 64, 256, 0, stream>>>(out, bboxes, out + 2 * NPIX);
}